// Round 3
// baseline (121.028 us; speedup 1.0000x reference)
//
#include <hip/hip_runtime.h>
#include <hip/hip_cooperative_groups.h>

namespace cg = cooperative_groups;

// DGCLoss: 1 - mean NDCG. N=384 rows, D=256 feats, M=383 off-diag cols.
//
// Round 17: single cooperative kernel. R16 showed deleting real work from
// dgc_trans changed nothing -> the controllable cost is dispatch boundaries
// (2 inter-kernel drains + 3 launch ramps), not kernel work. Fold the three
// kernels into one cooperative launch with 2 grid.sync()s:
//   Phase A: blocks 0..23 transpose+normalize -> XT[k][row], invn_g (R16 code).
//   Phase B: all 192 blocks: R16 dgc_fused body verbatim (bit-identical).
//   Phase C: block 0: out = 1 - mean(ndcg).

#define NN 384
#define DD 256
#define MM 383
// exp(-d*1000) == exp2(s_i - s_j) with s = ((cos+1)*0.5) * 1000*log2(e)
#define HSCALE 721.3475204444817f   // 0.5 * 1000 * log2(e)
#define NBUCK  256
#define BSCALE 0.1767955801104972f  // 256 / 1448  (values in [0, 1442.7])
#define WWIN   6.0f                 // soft-window half-width in s-units

__global__ __launch_bounds__(768) void dgc_all(const float* __restrict__ x,
                                               const int* __restrict__ gt,
                                               float* __restrict__ XT,
                                               float* __restrict__ invn_g,
                                               float* __restrict__ ndcg,
                                               float* __restrict__ out) {
    // Phase A LDS
    __shared__ float xs_t[16][260];     // +4 pad: conflict-free
    __shared__ float invn_s[16];
    // Phase B LDS
    __shared__ float  xs[2][DD];        // normalized rows n0, n0+1
    __shared__ float4 pacc[2][8][96];   // [row][k-chunk][j4] partial dots
    __shared__ float  srow[2][NN];
    __shared__ float  vsort[2][NN];
    __shared__ int    sidx[2][NN];
    __shared__ int    hist[2][NBUCK];
    __shared__ int    pre[2][NBUCK + 1];
    __shared__ int    cnt[6];
    __shared__ int    cum[2][6];
    __shared__ float  redd[12];
    __shared__ float  idr[12][2];       // per-wave idcg partials (waves 0,6 stay 0)

    cg::grid_group grid = cg::this_grid();

    const int t    = threadIdx.x;
    const int lane = t & 63;
    const int wave = t >> 6;

    // ================= Phase A: transpose + normalize (blocks 0..23) =====
    if (blockIdx.x < 24) {
        const int r0 = blockIdx.x * 16;
        for (int f = t; f < 1024; f += 768) {      // 1024 float4 of the tile
            int rr = f >> 6, c4 = f & 63;
            float4 v = ((const float4*)(x + (size_t)(r0 + rr) * DD))[c4];
            xs_t[rr][c4 * 4 + 0] = v.x; xs_t[rr][c4 * 4 + 1] = v.y;
            xs_t[rr][c4 * 4 + 2] = v.z; xs_t[rr][c4 * 4 + 3] = v.w;
        }
        __syncthreads();
        if (t < 256) {                  // row norms: 16 threads per row
            const int rr = t >> 4, sub = t & 15;
            float s = 0.0f;
            #pragma unroll
            for (int m = 0; m < 16; ++m) {
                float v = xs_t[rr][sub * 16 + m];
                s = fmaf(v, v, s);
            }
            #pragma unroll
            for (int off = 8; off > 0; off >>= 1) s += __shfl_xor(s, off, 64);
            if (sub == 0) invn_s[rr] = __builtin_amdgcn_rsqf(fmaxf(s, 1e-16f));
        }
        __syncthreads();
        if (t < 16) invn_g[r0 + t] = invn_s[t];
        if (t < 256) {                  // normalized transpose XT[k][r0+rr]
            const int rr = t & 15;
            const int kk = t >> 4;
            const float inv = invn_s[rr];
            #pragma unroll
            for (int i = 0; i < 16; ++i) {
                int k = i * 16 + kk;
                XT[(size_t)k * NN + r0 + rr] = xs_t[rr][k] * inv;
            }
        }
    }
    grid.sync();

    // ================= Phase B: fused per-row-pair pipeline ==============
    const int n0 = blockIdx.x * 2;

    // ---- S0: init ----
    if (t < 128) {
        const int rr = t >> 6;
        const float inv = invn_g[n0 + rr];
        float4 v = ((const float4*)(x + (size_t)(n0 + rr) * DD))[t & 63];
        v.x *= inv; v.y *= inv; v.z *= inv; v.w *= inv;
        ((float4*)xs[rr])[t & 63] = v;
    }
    if (t < 512) ((int*)hist)[t] = 0;
    if (t < 6)  cnt[t] = 0;
    if (t < 24) ((float*)idr)[t] = 0.0f;
    __syncthreads();

    // ---- S1: gt histogram (overlaps gram) + gram into pacc ----
    if (t < NN) atomicAdd(&cnt[gt[t]], 1);

    {   // j4 = t%96 (4 cols), kc = t/96 (8 chunks of 32 k's).
        const int j4 = t % 96;
        const int kc = t / 96;                 // 0..7
        const float4* XT4 = (const float4*)XT;
        float4 a0 = {0.f, 0.f, 0.f, 0.f};
        float4 a1 = {0.f, 0.f, 0.f, 0.f};
        const int k0 = kc * 32;
        #pragma unroll 8
        for (int m = 0; m < 32; ++m) {
            const int k = k0 + m;
            float4 b = XT4[(size_t)k * 96 + j4];   // coalesced, loaded once
            float s0 = xs[0][k];
            float s1 = xs[1][k];
            a0.x = fmaf(s0, b.x, a0.x); a0.y = fmaf(s0, b.y, a0.y);
            a0.z = fmaf(s0, b.z, a0.z); a0.w = fmaf(s0, b.w, a0.w);
            a1.x = fmaf(s1, b.x, a1.x); a1.y = fmaf(s1, b.y, a1.y);
            a1.z = fmaf(s1, b.z, a1.z); a1.w = fmaf(s1, b.w, a1.w);
        }
        pacc[0][kc][j4] = a0;
        pacc[1][kc][j4] = a1;
    }
    __syncthreads();

    const int r = t / 384;                 // row-half: waves 0-5 -> 0, 6-11 -> 1
    const int u = t - r * 384;             // 0..383

    // ---- S2: cum tables (threads 0,1) + reduce pacc + bucket ----
    if (t < 2) {
        const int gv = gt[n0 + t];
        int h[6];
        #pragma unroll
        for (int g = 0; g < 6; ++g) h[g] = 0;
        #pragma unroll
        for (int v = 0; v < 6; ++v) {
            int d = v - gv; d = d < 0 ? -d : d;
            h[d] += cnt[v];
        }
        h[0] -= 1;                         // remove self term
        int s = 0;
        #pragma unroll
        for (int g = 0; g < 6; ++g) { s += h[g]; cum[t][g] = s; }
    }

    {   // reduce 8 k-chunks; flat float view per row: [kc*384 + u]
        const float* pf = (const float*)pacc[r];
        float dot = 0.0f;
        #pragma unroll
        for (int c = 0; c < 8; ++c) dot += pf[c * 384 + u];
        srow[r][u] = fmaf(dot, HSCALE, HSCALE);
    }
    __syncthreads();

    // ---- counting sort per row ----
    const float vraw = srow[r][u];
    int b = (int)(vraw * BSCALE);
    b = b < 0 ? 0 : (b > NBUCK - 1 ? NBUCK - 1 : b);
    const int slot = atomicAdd(&hist[r][b], 1);
    __syncthreads();

    // ---- S3: hist scan (waves 0,6) || per-block idcg p-loop (others) ----
    if (wave == 0 || wave == 6) {
        const int rr = wave / 6;
        const int s0 = hist[rr][lane * 4 + 0], s1 = hist[rr][lane * 4 + 1];
        const int s2 = hist[rr][lane * 4 + 2], s3 = hist[rr][lane * 4 + 3];
        const int sum = s0 + s1 + s2 + s3;
        int inc = sum;
        #pragma unroll
        for (int off = 1; off < 64; off <<= 1) {
            int uu = __shfl_up(inc, off, 64);
            if (lane >= off) inc += uu;
        }
        const int base = inc - sum;
        pre[rr][lane * 4 + 0] = base;
        pre[rr][lane * 4 + 1] = base + s0;
        pre[rr][lane * 4 + 2] = base + s0 + s1;
        pre[rr][lane * 4 + 3] = base + s0 + s1 + s2;
        if (lane == 63) pre[rr][NBUCK] = inc;    // = 384
    } else {
        // waves 1-5 -> p in [0,320); waves 7-11 -> p in [320,640); p<383
        const int p = (wave < 6) ? (wave - 1) * 64 + lane
                                 : 320 + (wave - 7) * 64 + lane;
        float a0 = 0.0f, a1 = 0.0f;
        if (p < MM) {
            const float invl = 1.0f / __builtin_amdgcn_logf((float)(p + 2));
            const int g0 = (p >= cum[0][0]) + (p >= cum[0][1]) + (p >= cum[0][2])
                         + (p >= cum[0][3]) + (p >= cum[0][4]);
            const int g1 = (p >= cum[1][0]) + (p >= cum[1][1]) + (p >= cum[1][2])
                         + (p >= cum[1][3]) + (p >= cum[1][4]);
            a0 = (float)((1 << (10 - g0)) - 1) * invl;
            a1 = (float)((1 << (10 - g1)) - 1) * invl;
        }
        #pragma unroll
        for (int off = 32; off > 0; off >>= 1) {
            a0 += __shfl_down(a0, off, 64);
            a1 += __shfl_down(a1, off, 64);
        }
        if (lane == 0) { idr[wave][0] = a0; idr[wave][1] = a1; }
    }
    __syncthreads();

    // ---- S4: scatter ----
    {
        const int pos = pre[r][b] + slot;
        vsort[r][pos] = vraw;
        sidx[r][pos]  = u;
    }
    __syncthreads();

    // ---- S5: soft window at sorted position u of row r ----
    const int   nrow  = n0 + r;
    const float ri    = vsort[r][u];
    const int   iorig = sidx[r][u];
    const float sn    = srow[r][nrow];

    int Blo = (int)((ri - WWIN) * BSCALE);
    int Bhi = (int)((ri + WWIN) * BSCALE);
    Blo = Blo < 0 ? 0 : (Blo > NBUCK - 1 ? NBUCK - 1 : Blo);
    Bhi = Bhi < 0 ? 0 : (Bhi > NBUCK - 1 ? NBUCK - 1 : Bhi);
    const int lo = pre[r][Blo];        // below: term ~ 0
    const int hi = pre[r][Bhi + 1];    // at/above: term ~ 1

    // pair-rcp: 1/(1+a) + 1/(1+b) = (2+(a+b)) * rcp(1+(a+b)+a*b)
    // window bounds |ri-v| <= ~18 => a,b <= 2.6e5, ab <= 7e10: fp32-safe.
    float acc = 0.0f;
    int q = lo;
    for (; q + 2 <= hi; q += 2) {
        float a  = __builtin_amdgcn_exp2f(ri - vsort[r][q]);
        float bb = __builtin_amdgcn_exp2f(ri - vsort[r][q + 1]);
        float e = a + bb;
        float f = a * bb;
        acc = fmaf(2.0f + e, __builtin_amdgcn_rcpf(1.0f + e + f), acc);
    }
    if (q < hi)
        acc += __builtin_amdgcn_rcpf(1.0f + __builtin_amdgcn_exp2f(ri - vsort[r][q]));
    float sum_all = (float)(NN - hi) + acc;

    // diagonal (c == nrow) correction, bucket-consistent with the window
    int bn = (int)(sn * BSCALE);
    bn = bn < 0 ? 0 : (bn > NBUCK - 1 ? NBUCK - 1 : bn);
    float cd = 0.0f;
    if (bn > Bhi)       cd = 1.0f;
    else if (bn >= Blo) cd = __builtin_amdgcn_rcpf(1.0f + __builtin_amdgcn_exp2f(ri - sn));
    // self term (sigma(0)=0.5) always in-window: ind = 1 + sum - 0.5 - cd
    const float ind = 0.5f + sum_all - cd;

    // ---- dcg term ----
    float dcg_i = 0.0f;
    if (iorig != nrow) {               // permutation covers all 383 real cols
        const int gd = gt[iorig] - gt[nrow];
        const int gg = gd < 0 ? -gd : gd;
        dcg_i = (float)((1 << (10 - gg)) - 1) / __builtin_amdgcn_logf(ind + 1.0f);
    }

    #pragma unroll
    for (int off = 32; off > 0; off >>= 1) dcg_i += __shfl_down(dcg_i, off, 64);
    if (lane == 0) redd[wave] = dcg_i;
    __syncthreads();

    // ---- S6: ndcg stores (idcg summed from per-wave partials) ----
    if (t == 0) {
        const float id = idr[1][0] + idr[2][0] + idr[3][0] + idr[4][0] + idr[5][0]
                       + idr[7][0] + idr[8][0] + idr[9][0] + idr[10][0] + idr[11][0];
        ndcg[n0] = (redd[0] + redd[1] + redd[2] + redd[3] + redd[4] + redd[5]) / id;
    }
    if (t == 384) {
        const float id = idr[1][1] + idr[2][1] + idr[3][1] + idr[4][1] + idr[5][1]
                       + idr[7][1] + idr[8][1] + idr[9][1] + idr[10][1] + idr[11][1];
        ndcg[n0 + 1] = (redd[6] + redd[7] + redd[8] + redd[9] + redd[10] + redd[11])
                       / id;
    }

    grid.sync();

    // ================= Phase C: final mean (block 0) =====================
    if (blockIdx.x == 0) {
        float nd = (t < NN) ? ndcg[t] : 0.0f;
        #pragma unroll
        for (int off = 32; off > 0; off >>= 1) nd += __shfl_down(nd, off, 64);
        if (lane == 0) redd[wave] = nd;
        __syncthreads();
        if (t == 0) {
            float s = 0.0f;
            #pragma unroll
            for (int w = 0; w < 6; ++w) s += redd[w];
            out[0] = 1.0f - s / (float)NN;
        }
    }
}

extern "C" void kernel_launch(void* const* d_in, const int* in_sizes, int n_in,
                              void* d_out, int out_size, void* d_ws, size_t ws_size,
                              hipStream_t stream) {
    const float* ranking = (const float*)d_in[0];
    const int*   gt      = (const int*)d_in[1];
    float*       out     = (float*)d_out;

    float* XT     = (float*)d_ws;                // 256*384
    float* invn_g = XT + (size_t)DD * NN;        // 384
    float* ndcg   = invn_g + NN;                 // 384

    void* args[] = {(void*)&ranking, (void*)&gt, (void*)&XT,
                    (void*)&invn_g, (void*)&ndcg, (void*)&out};
    hipLaunchCooperativeKernel((void*)dgc_all, dim3(NN / 2), dim3(768),
                               args, 0, stream);
}

// Round 4
// 71.508 us; speedup vs baseline: 1.6925x; 1.6925x over previous
//
#include <hip/hip_runtime.h>

// DGCLoss: 1 - mean NDCG. N=384 rows, D=256 feats, M=383 off-diag cols.
//
// Round 18: R17's cooperative fusion was decisively bad (grid.sync ~15-20us
// each on 8 XCDs; kernel visible at 50us with 6.5% VALUBusy). Revert to the
// proven R16 two-big-kernel structure and delete the THIRD dispatch instead:
//   - dgc_trans zeroes {gsum, gticket} (stream order makes it visible).
//   - dgc_fused finalizes via last-block pattern: one atomicAdd of the
//     block's nd0+nd1, threadfence, ticket; ticket==191 reads the total
//     (atomicAdd(gsum,0)) and writes out. dgc_final + its boundary gone.
//   dgc_trans : 24 blocks: transpose+normalize -> XT[k][row], invn_g; init.
//   dgc_fused : block = rows (2b,2b+1): shared XT gram -> 2 srows, counting
//               sorts, pair-rcp soft window, per-block idcg, atomic finalize.

#define NN 384
#define DD 256
#define MM 383
// exp(-d*1000) == exp2(s_i - s_j) with s = ((cos+1)*0.5) * 1000*log2(e)
#define HSCALE 721.3475204444817f   // 0.5 * 1000 * log2(e)
#define NBUCK  256
#define BSCALE 0.1767955801104972f  // 256 / 1448  (values in [0, 1442.7])
#define WWIN   6.0f                 // soft-window half-width in s-units

__global__ __launch_bounds__(256) void dgc_trans(const float* __restrict__ x,
                                                 float* __restrict__ XT,
                                                 float* __restrict__ invn_g,
                                                 float* __restrict__ gsum,
                                                 int* __restrict__ gticket) {
    __shared__ float xs[16][260];   // +4 pad: conflict-free
    __shared__ float invn[16];
    const int t  = threadIdx.x;
    const int r0 = blockIdx.x * 16;

    if (blockIdx.x == 0 && t == 0) { *gsum = 0.0f; *gticket = 0; }

    #pragma unroll
    for (int i = 0; i < 4; ++i) {
        int f = t + i * 256;            // float4 unit 0..1023
        int r = f >> 6, c4 = f & 63;
        float4 v = ((const float4*)(x + (size_t)(r0 + r) * DD))[c4];
        xs[r][c4 * 4 + 0] = v.x; xs[r][c4 * 4 + 1] = v.y;
        xs[r][c4 * 4 + 2] = v.z; xs[r][c4 * 4 + 3] = v.w;
    }
    __syncthreads();

    {   // row norms: 16 threads per row
        const int r = t >> 4, sub = t & 15;
        float s = 0.0f;
        #pragma unroll
        for (int m = 0; m < 16; ++m) {
            float v = xs[r][sub * 16 + m];
            s = fmaf(v, v, s);
        }
        #pragma unroll
        for (int off = 8; off > 0; off >>= 1) s += __shfl_xor(s, off, 64);
        if (sub == 0) invn[r] = __builtin_amdgcn_rsqf(fmaxf(s, 1e-16f));
    }
    __syncthreads();

    if (t < 16) invn_g[r0 + t] = invn[t];

    {   // normalized transpose XT[k][r0+r]
        const int r  = t & 15;
        const int kk = t >> 4;
        const float inv = invn[r];
        #pragma unroll
        for (int i = 0; i < 16; ++i) {
            int k = i * 16 + kk;
            XT[(size_t)k * NN + r0 + r] = xs[r][k] * inv;
        }
    }
}

__global__ __launch_bounds__(768) void dgc_fused(const float* __restrict__ XT,
                                                 const float* __restrict__ x,
                                                 const float* __restrict__ invn_g,
                                                 const int* __restrict__ gt,
                                                 float* __restrict__ gsum,
                                                 int* __restrict__ gticket,
                                                 float* __restrict__ out) {
    __shared__ float  xs[2][DD];        // normalized rows n0, n0+1
    __shared__ float4 pacc[2][8][96];   // [row][k-chunk][j4] partial dots
    __shared__ float  srow[2][NN];
    __shared__ float  vsort[2][NN];
    __shared__ int    sidx[2][NN];
    __shared__ int    hist[2][NBUCK];
    __shared__ int    pre[2][NBUCK + 1];
    __shared__ int    cnt[6];
    __shared__ int    cum[2][6];
    __shared__ float  redd[12];
    __shared__ float  idr[12][2];       // per-wave idcg partials (waves 0,6 stay 0)

    const int n0   = blockIdx.x * 2;
    const int t    = threadIdx.x;
    const int lane = t & 63;
    const int wave = t >> 6;

    // ---- S0: init ----
    if (t < 128) {
        const int rr = t >> 6;
        const float inv = invn_g[n0 + rr];
        float4 v = ((const float4*)(x + (size_t)(n0 + rr) * DD))[t & 63];
        v.x *= inv; v.y *= inv; v.z *= inv; v.w *= inv;
        ((float4*)xs[rr])[t & 63] = v;
    }
    if (t < 512) ((int*)hist)[t] = 0;
    if (t < 6)  cnt[t] = 0;
    if (t < 24) ((float*)idr)[t] = 0.0f;
    __syncthreads();

    // ---- S1: gt histogram (overlaps gram) + gram into pacc ----
    if (t < NN) atomicAdd(&cnt[gt[t]], 1);

    {   // j4 = t%96 (4 cols), kc = t/96 (8 chunks of 32 k's).
        const int j4 = t % 96;
        const int kc = t / 96;                 // 0..7
        const float4* XT4 = (const float4*)XT;
        float4 a0 = {0.f, 0.f, 0.f, 0.f};
        float4 a1 = {0.f, 0.f, 0.f, 0.f};
        const int k0 = kc * 32;
        #pragma unroll 8
        for (int m = 0; m < 32; ++m) {
            const int k = k0 + m;
            float4 b = XT4[(size_t)k * 96 + j4];   // coalesced, loaded once
            float s0 = xs[0][k];
            float s1 = xs[1][k];
            a0.x = fmaf(s0, b.x, a0.x); a0.y = fmaf(s0, b.y, a0.y);
            a0.z = fmaf(s0, b.z, a0.z); a0.w = fmaf(s0, b.w, a0.w);
            a1.x = fmaf(s1, b.x, a1.x); a1.y = fmaf(s1, b.y, a1.y);
            a1.z = fmaf(s1, b.z, a1.z); a1.w = fmaf(s1, b.w, a1.w);
        }
        pacc[0][kc][j4] = a0;
        pacc[1][kc][j4] = a1;
    }
    __syncthreads();

    const int r = t / 384;                 // row-half: waves 0-5 -> 0, 6-11 -> 1
    const int u = t - r * 384;             // 0..383

    // ---- S2: cum tables (threads 0,1) + reduce pacc + bucket ----
    if (t < 2) {
        const int gv = gt[n0 + t];
        int h[6];
        #pragma unroll
        for (int g = 0; g < 6; ++g) h[g] = 0;
        #pragma unroll
        for (int v = 0; v < 6; ++v) {
            int d = v - gv; d = d < 0 ? -d : d;
            h[d] += cnt[v];
        }
        h[0] -= 1;                         // remove self term
        int s = 0;
        #pragma unroll
        for (int g = 0; g < 6; ++g) { s += h[g]; cum[t][g] = s; }
    }

    {   // reduce 8 k-chunks; flat float view per row: [kc*384 + u]
        const float* pf = (const float*)pacc[r];
        float dot = 0.0f;
        #pragma unroll
        for (int c = 0; c < 8; ++c) dot += pf[c * 384 + u];
        srow[r][u] = fmaf(dot, HSCALE, HSCALE);
    }
    __syncthreads();

    // ---- counting sort per row ----
    const float vraw = srow[r][u];
    int b = (int)(vraw * BSCALE);
    b = b < 0 ? 0 : (b > NBUCK - 1 ? NBUCK - 1 : b);
    const int slot = atomicAdd(&hist[r][b], 1);
    __syncthreads();

    // ---- S3: hist scan (waves 0,6) || per-block idcg p-loop (others) ----
    if (wave == 0 || wave == 6) {
        const int rr = wave / 6;
        const int s0 = hist[rr][lane * 4 + 0], s1 = hist[rr][lane * 4 + 1];
        const int s2 = hist[rr][lane * 4 + 2], s3 = hist[rr][lane * 4 + 3];
        const int sum = s0 + s1 + s2 + s3;
        int inc = sum;
        #pragma unroll
        for (int off = 1; off < 64; off <<= 1) {
            int uu = __shfl_up(inc, off, 64);
            if (lane >= off) inc += uu;
        }
        const int base = inc - sum;
        pre[rr][lane * 4 + 0] = base;
        pre[rr][lane * 4 + 1] = base + s0;
        pre[rr][lane * 4 + 2] = base + s0 + s1;
        pre[rr][lane * 4 + 3] = base + s0 + s1 + s2;
        if (lane == 63) pre[rr][NBUCK] = inc;    // = 384
    } else {
        // waves 1-5 -> p in [0,320); waves 7-11 -> p in [320,640); p<383
        const int p = (wave < 6) ? (wave - 1) * 64 + lane
                                 : 320 + (wave - 7) * 64 + lane;
        float a0 = 0.0f, a1 = 0.0f;
        if (p < MM) {
            const float invl = 1.0f / __builtin_amdgcn_logf((float)(p + 2));
            const int g0 = (p >= cum[0][0]) + (p >= cum[0][1]) + (p >= cum[0][2])
                         + (p >= cum[0][3]) + (p >= cum[0][4]);
            const int g1 = (p >= cum[1][0]) + (p >= cum[1][1]) + (p >= cum[1][2])
                         + (p >= cum[1][3]) + (p >= cum[1][4]);
            a0 = (float)((1 << (10 - g0)) - 1) * invl;
            a1 = (float)((1 << (10 - g1)) - 1) * invl;
        }
        #pragma unroll
        for (int off = 32; off > 0; off >>= 1) {
            a0 += __shfl_down(a0, off, 64);
            a1 += __shfl_down(a1, off, 64);
        }
        if (lane == 0) { idr[wave][0] = a0; idr[wave][1] = a1; }
    }
    __syncthreads();

    // ---- S4: scatter ----
    {
        const int pos = pre[r][b] + slot;
        vsort[r][pos] = vraw;
        sidx[r][pos]  = u;
    }
    __syncthreads();

    // ---- S5: soft window at sorted position u of row r ----
    const int   nrow  = n0 + r;
    const float ri    = vsort[r][u];
    const int   iorig = sidx[r][u];
    const float sn    = srow[r][nrow];

    int Blo = (int)((ri - WWIN) * BSCALE);
    int Bhi = (int)((ri + WWIN) * BSCALE);
    Blo = Blo < 0 ? 0 : (Blo > NBUCK - 1 ? NBUCK - 1 : Blo);
    Bhi = Bhi < 0 ? 0 : (Bhi > NBUCK - 1 ? NBUCK - 1 : Bhi);
    const int lo = pre[r][Blo];        // below: term ~ 0
    const int hi = pre[r][Bhi + 1];    // at/above: term ~ 1

    // pair-rcp: 1/(1+a) + 1/(1+b) = (2+(a+b)) * rcp(1+(a+b)+a*b)
    // window bounds |ri-v| <= ~18 => a,b <= 2.6e5, ab <= 7e10: fp32-safe.
    float acc = 0.0f;
    int q = lo;
    for (; q + 2 <= hi; q += 2) {
        float a  = __builtin_amdgcn_exp2f(ri - vsort[r][q]);
        float bb = __builtin_amdgcn_exp2f(ri - vsort[r][q + 1]);
        float e = a + bb;
        float f = a * bb;
        acc = fmaf(2.0f + e, __builtin_amdgcn_rcpf(1.0f + e + f), acc);
    }
    if (q < hi)
        acc += __builtin_amdgcn_rcpf(1.0f + __builtin_amdgcn_exp2f(ri - vsort[r][q]));
    float sum_all = (float)(NN - hi) + acc;

    // diagonal (c == nrow) correction, bucket-consistent with the window
    int bn = (int)(sn * BSCALE);
    bn = bn < 0 ? 0 : (bn > NBUCK - 1 ? NBUCK - 1 : bn);
    float cd = 0.0f;
    if (bn > Bhi)       cd = 1.0f;
    else if (bn >= Blo) cd = __builtin_amdgcn_rcpf(1.0f + __builtin_amdgcn_exp2f(ri - sn));
    // self term (sigma(0)=0.5) always in-window: ind = 1 + sum - 0.5 - cd
    const float ind = 0.5f + sum_all - cd;

    // ---- dcg term ----
    float dcg_i = 0.0f;
    if (iorig != nrow) {               // permutation covers all 383 real cols
        const int gd = gt[iorig] - gt[nrow];
        const int gg = gd < 0 ? -gd : gd;
        dcg_i = (float)((1 << (10 - gg)) - 1) / __builtin_amdgcn_logf(ind + 1.0f);
    }

    #pragma unroll
    for (int off = 32; off > 0; off >>= 1) dcg_i += __shfl_down(dcg_i, off, 64);
    if (lane == 0) redd[wave] = dcg_i;
    __syncthreads();

    // ---- S6: last-block finalize (replaces ndcg stores + dgc_final) ----
    if (t == 0) {
        const float id0 = idr[1][0] + idr[2][0] + idr[3][0] + idr[4][0] + idr[5][0]
                        + idr[7][0] + idr[8][0] + idr[9][0] + idr[10][0] + idr[11][0];
        const float id1 = idr[1][1] + idr[2][1] + idr[3][1] + idr[4][1] + idr[5][1]
                        + idr[7][1] + idr[8][1] + idr[9][1] + idr[10][1] + idr[11][1];
        const float nd0 = (redd[0] + redd[1] + redd[2] + redd[3] + redd[4] + redd[5])
                          / id0;
        const float nd1 = (redd[6] + redd[7] + redd[8] + redd[9] + redd[10] + redd[11])
                          / id1;
        atomicAdd(gsum, nd0 + nd1);
        __threadfence();                       // order gsum add before ticket
        const int old = atomicAdd(gticket, 1);
        if (old == NN / 2 - 1) {               // last block: all adds visible
            const float tot = atomicAdd(gsum, 0.0f);   // coherent read
            out[0] = 1.0f - tot / (float)NN;
        }
    }
}

extern "C" void kernel_launch(void* const* d_in, const int* in_sizes, int n_in,
                              void* d_out, int out_size, void* d_ws, size_t ws_size,
                              hipStream_t stream) {
    const float* ranking = (const float*)d_in[0];
    const int*   gt      = (const int*)d_in[1];
    float*       out     = (float*)d_out;

    float* XT      = (float*)d_ws;               // 256*384
    float* invn_g  = XT + (size_t)DD * NN;       // 384
    float* gsum    = invn_g + NN;                // 1
    int*   gticket = (int*)(gsum + 1);           // 1

    dgc_trans<<<24, 256, 0, stream>>>(ranking, XT, invn_g, gsum, gticket);
    dgc_fused<<<NN / 2, 768, 0, stream>>>(XT, ranking, invn_g, gt,
                                          gsum, gticket, out);
}

// Round 5
// 68.624 us; speedup vs baseline: 1.7636x; 1.0420x over previous
//
#include <hip/hip_runtime.h>

// DGCLoss: 1 - mean NDCG. N=384 rows, D=256 feats, M=383 off-diag cols.
//
// Round 19: consolidation at the best-known structure (R16 family, 69.4-69.8)
// after the structural sweep: R15 raw-gram +14, R17 coop grid.sync +51,
// R18 atomic-finalize tail +2. Kernel slowdowns transfer 1:1 into dur_us but
// ~1-2us deletions are invisible -> plateau = fill(40us) + fixed overhead +
// ~12-15us kernels/gaps. This round takes the strictly-free wins only:
//   - fused: barrier between srow-write and bucket REMOVED (vraw is the
//     thread's own value -> register; the post-atomic barrier still guards
//     the scan). One fewer full-block barrier.
//   - fused: dead idr zero-init removed (slots 0/6 never summed).
//   dgc_trans : 24 blocks: transpose+normalize -> XT[k][row], invn_g[row].
//   dgc_fused : block = rows (2b,2b+1): shared XT gram -> 2 srows, counting
//               sorts, pair-rcp soft window, per-block idcg, ndcg stores.
//   dgc_final : 1 block: out = 1 - mean(ndcg).

#define NN 384
#define DD 256
#define MM 383
// exp(-d*1000) == exp2(s_i - s_j) with s = ((cos+1)*0.5) * 1000*log2(e)
#define HSCALE 721.3475204444817f   // 0.5 * 1000 * log2(e)
#define NBUCK  256
#define BSCALE 0.1767955801104972f  // 256 / 1448  (values in [0, 1442.7])
#define WWIN   6.0f                 // soft-window half-width in s-units

__global__ __launch_bounds__(256) void dgc_trans(const float* __restrict__ x,
                                                 float* __restrict__ XT,
                                                 float* __restrict__ invn_g) {
    __shared__ float xs[16][260];   // +4 pad: conflict-free
    __shared__ float invn[16];
    const int t  = threadIdx.x;
    const int r0 = blockIdx.x * 16;

    #pragma unroll
    for (int i = 0; i < 4; ++i) {
        int f = t + i * 256;            // float4 unit 0..1023
        int r = f >> 6, c4 = f & 63;
        float4 v = ((const float4*)(x + (size_t)(r0 + r) * DD))[c4];
        xs[r][c4 * 4 + 0] = v.x; xs[r][c4 * 4 + 1] = v.y;
        xs[r][c4 * 4 + 2] = v.z; xs[r][c4 * 4 + 3] = v.w;
    }
    __syncthreads();

    {   // row norms: 16 threads per row
        const int r = t >> 4, sub = t & 15;
        float s = 0.0f;
        #pragma unroll
        for (int m = 0; m < 16; ++m) {
            float v = xs[r][sub * 16 + m];
            s = fmaf(v, v, s);
        }
        #pragma unroll
        for (int off = 8; off > 0; off >>= 1) s += __shfl_xor(s, off, 64);
        if (sub == 0) invn[r] = __builtin_amdgcn_rsqf(fmaxf(s, 1e-16f));
    }
    __syncthreads();

    if (t < 16) invn_g[r0 + t] = invn[t];

    {   // normalized transpose XT[k][r0+r]
        const int r  = t & 15;
        const int kk = t >> 4;
        const float inv = invn[r];
        #pragma unroll
        for (int i = 0; i < 16; ++i) {
            int k = i * 16 + kk;
            XT[(size_t)k * NN + r0 + r] = xs[r][k] * inv;
        }
    }
}

__global__ __launch_bounds__(768) void dgc_fused(const float* __restrict__ XT,
                                                 const float* __restrict__ x,
                                                 const float* __restrict__ invn_g,
                                                 const int* __restrict__ gt,
                                                 float* __restrict__ ndcg) {
    __shared__ float  xs[2][DD];        // normalized rows n0, n0+1
    __shared__ float4 pacc[2][8][96];   // [row][k-chunk][j4] partial dots
    __shared__ float  srow[2][NN];
    __shared__ float  vsort[2][NN];
    __shared__ int    sidx[2][NN];
    __shared__ int    hist[2][NBUCK];
    __shared__ int    pre[2][NBUCK + 1];
    __shared__ int    cnt[6];
    __shared__ int    cum[2][6];
    __shared__ float  redd[12];
    __shared__ float  idr[12][2];       // per-wave idcg partials (0/6 unused)

    const int n0   = blockIdx.x * 2;
    const int t    = threadIdx.x;
    const int lane = t & 63;
    const int wave = t >> 6;

    // ---- S0: init ----
    if (t < 128) {
        const int rr = t >> 6;
        const float inv = invn_g[n0 + rr];
        float4 v = ((const float4*)(x + (size_t)(n0 + rr) * DD))[t & 63];
        v.x *= inv; v.y *= inv; v.z *= inv; v.w *= inv;
        ((float4*)xs[rr])[t & 63] = v;
    }
    if (t < 512) ((int*)hist)[t] = 0;
    if (t < 6)  cnt[t] = 0;
    __syncthreads();

    // ---- S1: gt histogram (overlaps gram) + gram into pacc ----
    if (t < NN) atomicAdd(&cnt[gt[t]], 1);

    {   // j4 = t%96 (4 cols), kc = t/96 (8 chunks of 32 k's).
        const int j4 = t % 96;
        const int kc = t / 96;                 // 0..7
        const float4* XT4 = (const float4*)XT;
        float4 a0 = {0.f, 0.f, 0.f, 0.f};
        float4 a1 = {0.f, 0.f, 0.f, 0.f};
        const int k0 = kc * 32;
        #pragma unroll 8
        for (int m = 0; m < 32; ++m) {
            const int k = k0 + m;
            float4 b = XT4[(size_t)k * 96 + j4];   // coalesced, loaded once
            float s0 = xs[0][k];
            float s1 = xs[1][k];
            a0.x = fmaf(s0, b.x, a0.x); a0.y = fmaf(s0, b.y, a0.y);
            a0.z = fmaf(s0, b.z, a0.z); a0.w = fmaf(s0, b.w, a0.w);
            a1.x = fmaf(s1, b.x, a1.x); a1.y = fmaf(s1, b.y, a1.y);
            a1.z = fmaf(s1, b.z, a1.z); a1.w = fmaf(s1, b.w, a1.w);
        }
        pacc[0][kc][j4] = a0;
        pacc[1][kc][j4] = a1;
    }
    __syncthreads();

    const int r = t / 384;                 // row-half: waves 0-5 -> 0, 6-11 -> 1
    const int u = t - r * 384;             // 0..383

    // ---- S2: cum tables (threads 0,1) + reduce pacc + bucket ----
    if (t < 2) {
        const int gv = gt[n0 + t];
        int h[6];
        #pragma unroll
        for (int g = 0; g < 6; ++g) h[g] = 0;
        #pragma unroll
        for (int v = 0; v < 6; ++v) {
            int d = v - gv; d = d < 0 ? -d : d;
            h[d] += cnt[v];
        }
        h[0] -= 1;                         // remove self term
        int s = 0;
        #pragma unroll
        for (int g = 0; g < 6; ++g) { s += h[g]; cum[t][g] = s; }
    }

    float vraw;
    {   // reduce 8 k-chunks; flat float view per row: [kc*384 + u]
        const float* pf = (const float*)pacc[r];
        float dot = 0.0f;
        #pragma unroll
        for (int c = 0; c < 8; ++c) dot += pf[c * 384 + u];
        vraw = fmaf(dot, HSCALE, HSCALE);
        srow[r][u] = vraw;                 // for sn reads in S5 (post-barrier)
    }
    // NOTE: no barrier here. vraw is this thread's own value (register);
    // the counting-sort bucket only needs hist zeroed (S0 barrier). The
    // barrier after the atomics still orders hist for the scan, and orders
    // srow/cum for their cross-thread readers.
    int b = (int)(vraw * BSCALE);
    b = b < 0 ? 0 : (b > NBUCK - 1 ? NBUCK - 1 : b);
    const int slot = atomicAdd(&hist[r][b], 1);
    __syncthreads();

    // ---- S3: hist scan (waves 0,6) || per-block idcg p-loop (others) ----
    if (wave == 0 || wave == 6) {
        const int rr = wave / 6;
        const int s0 = hist[rr][lane * 4 + 0], s1 = hist[rr][lane * 4 + 1];
        const int s2 = hist[rr][lane * 4 + 2], s3 = hist[rr][lane * 4 + 3];
        const int sum = s0 + s1 + s2 + s3;
        int inc = sum;
        #pragma unroll
        for (int off = 1; off < 64; off <<= 1) {
            int uu = __shfl_up(inc, off, 64);
            if (lane >= off) inc += uu;
        }
        const int base = inc - sum;
        pre[rr][lane * 4 + 0] = base;
        pre[rr][lane * 4 + 1] = base + s0;
        pre[rr][lane * 4 + 2] = base + s0 + s1;
        pre[rr][lane * 4 + 3] = base + s0 + s1 + s2;
        if (lane == 63) pre[rr][NBUCK] = inc;    // = 384
    } else {
        // waves 1-5 -> p in [0,320); waves 7-11 -> p in [320,640); p<383
        const int p = (wave < 6) ? (wave - 1) * 64 + lane
                                 : 320 + (wave - 7) * 64 + lane;
        float a0 = 0.0f, a1 = 0.0f;
        if (p < MM) {
            const float invl = 1.0f / __builtin_amdgcn_logf((float)(p + 2));
            const int g0 = (p >= cum[0][0]) + (p >= cum[0][1]) + (p >= cum[0][2])
                         + (p >= cum[0][3]) + (p >= cum[0][4]);
            const int g1 = (p >= cum[1][0]) + (p >= cum[1][1]) + (p >= cum[1][2])
                         + (p >= cum[1][3]) + (p >= cum[1][4]);
            a0 = (float)((1 << (10 - g0)) - 1) * invl;
            a1 = (float)((1 << (10 - g1)) - 1) * invl;
        }
        #pragma unroll
        for (int off = 32; off > 0; off >>= 1) {
            a0 += __shfl_down(a0, off, 64);
            a1 += __shfl_down(a1, off, 64);
        }
        if (lane == 0) { idr[wave][0] = a0; idr[wave][1] = a1; }
    }
    __syncthreads();

    // ---- S4: scatter ----
    {
        const int pos = pre[r][b] + slot;
        vsort[r][pos] = vraw;
        sidx[r][pos]  = u;
    }
    __syncthreads();

    // ---- S5: soft window at sorted position u of row r ----
    const int   nrow  = n0 + r;
    const float ri    = vsort[r][u];
    const int   iorig = sidx[r][u];
    const float sn    = srow[r][nrow];

    int Blo = (int)((ri - WWIN) * BSCALE);
    int Bhi = (int)((ri + WWIN) * BSCALE);
    Blo = Blo < 0 ? 0 : (Blo > NBUCK - 1 ? NBUCK - 1 : Blo);
    Bhi = Bhi < 0 ? 0 : (Bhi > NBUCK - 1 ? NBUCK - 1 : Bhi);
    const int lo = pre[r][Blo];        // below: term ~ 0
    const int hi = pre[r][Bhi + 1];    // at/above: term ~ 1

    // pair-rcp: 1/(1+a) + 1/(1+b) = (2+(a+b)) * rcp(1+(a+b)+a*b)
    // window bounds |ri-v| <= ~18 => a,b <= 2.6e5, ab <= 7e10: fp32-safe.
    float acc = 0.0f;
    int q = lo;
    for (; q + 2 <= hi; q += 2) {
        float a  = __builtin_amdgcn_exp2f(ri - vsort[r][q]);
        float bb = __builtin_amdgcn_exp2f(ri - vsort[r][q + 1]);
        float e = a + bb;
        float f = a * bb;
        acc = fmaf(2.0f + e, __builtin_amdgcn_rcpf(1.0f + e + f), acc);
    }
    if (q < hi)
        acc += __builtin_amdgcn_rcpf(1.0f + __builtin_amdgcn_exp2f(ri - vsort[r][q]));
    float sum_all = (float)(NN - hi) + acc;

    // diagonal (c == nrow) correction, bucket-consistent with the window
    int bn = (int)(sn * BSCALE);
    bn = bn < 0 ? 0 : (bn > NBUCK - 1 ? NBUCK - 1 : bn);
    float cd = 0.0f;
    if (bn > Bhi)       cd = 1.0f;
    else if (bn >= Blo) cd = __builtin_amdgcn_rcpf(1.0f + __builtin_amdgcn_exp2f(ri - sn));
    // self term (sigma(0)=0.5) always in-window: ind = 1 + sum - 0.5 - cd
    const float ind = 0.5f + sum_all - cd;

    // ---- dcg term ----
    float dcg_i = 0.0f;
    if (iorig != nrow) {               // permutation covers all 383 real cols
        const int gd = gt[iorig] - gt[nrow];
        const int gg = gd < 0 ? -gd : gd;
        dcg_i = (float)((1 << (10 - gg)) - 1) / __builtin_amdgcn_logf(ind + 1.0f);
    }

    #pragma unroll
    for (int off = 32; off > 0; off >>= 1) dcg_i += __shfl_down(dcg_i, off, 64);
    if (lane == 0) redd[wave] = dcg_i;
    __syncthreads();

    // ---- S6: ndcg stores (idcg summed from per-wave partials) ----
    if (t == 0) {
        const float id = idr[1][0] + idr[2][0] + idr[3][0] + idr[4][0] + idr[5][0]
                       + idr[7][0] + idr[8][0] + idr[9][0] + idr[10][0] + idr[11][0];
        ndcg[n0] = (redd[0] + redd[1] + redd[2] + redd[3] + redd[4] + redd[5]) / id;
    }
    if (t == 384) {
        const float id = idr[1][1] + idr[2][1] + idr[3][1] + idr[4][1] + idr[5][1]
                       + idr[7][1] + idr[8][1] + idr[9][1] + idr[10][1] + idr[11][1];
        ndcg[n0 + 1] = (redd[6] + redd[7] + redd[8] + redd[9] + redd[10] + redd[11])
                       / id;
    }
}

__global__ __launch_bounds__(384) void dgc_final(const float* __restrict__ ndcg,
                                                 float* __restrict__ out) {
    __shared__ float red[6];
    const int t    = threadIdx.x;
    const int lane = t & 63;
    const int wave = t >> 6;
    float nd = ndcg[t];
    #pragma unroll
    for (int off = 32; off > 0; off >>= 1) nd += __shfl_down(nd, off, 64);
    if (lane == 0) red[wave] = nd;
    __syncthreads();
    if (t == 0) {
        float s = 0.0f;
        for (int w = 0; w < 6; ++w) s += red[w];
        out[0] = 1.0f - s / (float)NN;
    }
}

extern "C" void kernel_launch(void* const* d_in, const int* in_sizes, int n_in,
                              void* d_out, int out_size, void* d_ws, size_t ws_size,
                              hipStream_t stream) {
    const float* ranking = (const float*)d_in[0];
    const int*   gt      = (const int*)d_in[1];
    float*       out     = (float*)d_out;

    float* XT     = (float*)d_ws;                // 256*384
    float* invn_g = XT + (size_t)DD * NN;        // 384
    float* ndcg   = invn_g + NN;                 // 384

    dgc_trans<<<24, 256, 0, stream>>>(ranking, XT, invn_g);
    dgc_fused<<<NN / 2, 768, 0, stream>>>(XT, ranking, invn_g, gt, ndcg);
    dgc_final<<<1, 384, 0, stream>>>(ndcg, out);
}